// Round 1
// baseline (215.556 us; speedup 1.0000x reference)
//
#include <hip/hip_runtime.h>

#define NB    16
#define CIN   64
#define COUT  64
#define HIN   66
#define WIN   66
#define HOUT  64
#define WOUT  64
#define KK    9

// weight [cout][cin][k]  ->  wT [k][cin][cout]  (contiguous cout rows)
__global__ __launch_bounds__(256) void repack_w_kernel(const float* __restrict__ w,
                                                       float* __restrict__ wT) {
    int i = blockIdx.x * 256 + threadIdx.x;
    if (i >= KK * CIN * COUT) return;
    int co = i & 63;
    int t  = i >> 6;
    int c  = t & 63;
    int k  = t >> 6;
    wT[i] = w[(co * CIN + c) * KK + k];
}

__global__ __launch_bounds__(256) void dconv_kernel(const float* __restrict__ inp,
                                                    const float* __restrict__ off,
                                                    const float* __restrict__ wT,
                                                    float* __restrict__ out) {
    const int tid = threadIdx.x;
    const int wo  = tid & 63;
    const int g   = tid >> 6;                    // wave index == cin-group (wave-uniform)
    const int n   = blockIdx.x >> 6;
    const int ho  = blockIdx.x & 63;
    const int cbase = __builtin_amdgcn_readfirstlane(g << 4);   // 16 cin per group

    float acc[COUT];
#pragma unroll
    for (int i = 0; i < COUT; ++i) acc[i] = 0.f;

    const float* inp_n = inp + n * (CIN * HIN * WIN);
    const float* off_p = off + ((n * (2 * KK)) * HOUT + ho) * WOUT + wo;

#pragma unroll 1
    for (int k = 0; k < KK; ++k) {
        float dy = off_p[(2 * k) * (HOUT * WOUT)];
        float dx = off_p[(2 * k + 1) * (HOUT * WOUT)];
        float py = (float)(ho + k / 3) + dy;      // sampling y
        float px = (float)(wo + k % 3) + dx;      // sampling x
        float y0f = floorf(py), x0f = floorf(px);
        float fy = py - y0f, fx = px - x0f;
        int y0 = (int)y0f, x0 = (int)x0f;         // exact: y0f already integral
        int y1 = y0 + 1,   x1 = x0 + 1;
        float vy0 = (y0 >= 0 && y0 < HIN) ? 1.f : 0.f;
        float vy1 = (y1 >= 0 && y1 < HIN) ? 1.f : 0.f;
        float vx0 = (x0 >= 0 && x0 < WIN) ? 1.f : 0.f;
        float vx1 = (x1 >= 0 && x1 < WIN) ? 1.f : 0.f;
        int y0c = min(max(y0, 0), HIN - 1);
        int y1c = min(max(y1, 0), HIN - 1);
        int x0c = min(max(x0, 0), WIN - 1);
        int x1c = min(max(x1, 0), WIN - 1);
        int o00 = y0c * WIN + x0c;
        int o01 = y0c * WIN + x1c;
        int o10 = y1c * WIN + x0c;
        int o11 = y1c * WIN + x1c;
        float w00 = (1.f - fy) * (1.f - fx) * vy0 * vx0;   // validity folded into weights
        float w01 = (1.f - fy) * fx         * vy0 * vx1;
        float w10 = fy * (1.f - fx)         * vy1 * vx0;
        float w11 = fy * fx                 * vy1 * vx1;

        const float* pc   = inp_n + cbase * (HIN * WIN);
        const float* wrow = wT + ((k * CIN + cbase) << 6);
#pragma unroll 4
        for (int c = 0; c < 16; ++c) {
            float v = w00 * pc[o00] + w01 * pc[o01] + w10 * pc[o10] + w11 * pc[o11];
#pragma unroll
            for (int co = 0; co < COUT; ++co)
                acc[co] = fmaf(v, wrow[co], acc[co]);
            pc   += HIN * WIN;
            wrow += COUT;
        }
    }

    // reduce the 4 cin-group partial sums: red[co][wo]
    __shared__ float red[COUT * WOUT];            // 16 KB
    for (int i = tid; i < COUT * WOUT; i += 256) red[i] = 0.f;
    __syncthreads();
#pragma unroll
    for (int co = 0; co < COUT; ++co)
        atomicAdd(&red[co * WOUT + wo], acc[co]); // native ds_add_f32, stride-1 across lanes
    __syncthreads();

    float* out_p = out + (n * COUT * HOUT + ho) * WOUT;
    for (int i = tid; i < COUT * WOUT; i += 256) {
        int co = i >> 6, w2 = i & 63;
        out_p[co * (HOUT * WOUT) + w2] = red[i];
    }
}

extern "C" void kernel_launch(void* const* d_in, const int* in_sizes, int n_in,
                              void* d_out, int out_size, void* d_ws, size_t ws_size,
                              hipStream_t stream) {
    const float* inp = (const float*)d_in[0];
    const float* off = (const float*)d_in[1];
    const float* w   = (const float*)d_in[2];
    float* wT  = (float*)d_ws;                    // 9*64*64*4 = 147456 B
    float* out = (float*)d_out;

    repack_w_kernel<<<(KK * CIN * COUT + 255) / 256, 256, 0, stream>>>(w, wT);
    dconv_kernel<<<NB * HOUT, 256, 0, stream>>>(inp, off, wT, out);
}

// Round 2
// 163.054 us; speedup vs baseline: 1.3220x; 1.3220x over previous
//
#include <hip/hip_runtime.h>

#define NB    16
#define CIN   64
#define COUT  64
#define HIN   66
#define WIN   66
#define HOUT  64
#define WOUT  64
#define KK    9
#define NXCD  8

// weight [cout][cin][k]  ->  wT [k][cin][cout]  (contiguous cout rows)
__global__ __launch_bounds__(256) void repack_w_kernel(const float* __restrict__ w,
                                                       float* __restrict__ wT) {
    int i = blockIdx.x * 256 + threadIdx.x;
    if (i >= KK * CIN * COUT) return;
    int co = i & 63;
    int t  = i >> 6;
    int c  = t & 63;
    int k  = t >> 6;
    wT[i] = w[(co * CIN + c) * KK + k];
}

__global__ __launch_bounds__(256) void dconv_kernel(const float* __restrict__ inp,
                                                    const float* __restrict__ off,
                                                    const float* __restrict__ wT,
                                                    float* __restrict__ out) {
    const int tid = threadIdx.x;
    const int wo  = tid & 63;
    const int g   = tid >> 6;                    // wave index == cin-group (wave-uniform)

    // XCD-aware chunked swizzle: hardware assigns physical block p to XCD p%8.
    // Remap so XCD x gets logical blocks [x*128, (x+1)*128) == 2 full batch
    // images (2.2 MB input) -> fits the per-XCD 4 MB L2. grid=1024, 1024%8==0
    // so the map is bijective.
    const int p = blockIdx.x;
    const int logical = (p & (NXCD - 1)) * (NB * HOUT / NXCD) + (p >> 3);
    const int n   = logical >> 6;
    const int ho  = logical & 63;
    const int cbase = __builtin_amdgcn_readfirstlane(g << 4);   // 16 cin per group

    float acc[COUT];
#pragma unroll
    for (int i = 0; i < COUT; ++i) acc[i] = 0.f;

    const float* inp_n = inp + n * (CIN * HIN * WIN);
    const float* off_p = off + ((n * (2 * KK)) * HOUT + ho) * WOUT + wo;

#pragma unroll 1
    for (int k = 0; k < KK; ++k) {
        float dy = off_p[(2 * k) * (HOUT * WOUT)];
        float dx = off_p[(2 * k + 1) * (HOUT * WOUT)];
        float py = (float)(ho + k / 3) + dy;      // sampling y
        float px = (float)(wo + k % 3) + dx;      // sampling x
        float y0f = floorf(py), x0f = floorf(px);
        float fy = py - y0f, fx = px - x0f;
        int y0 = (int)y0f, x0 = (int)x0f;
        int y1 = y0 + 1,   x1 = x0 + 1;
        float vy0 = (y0 >= 0 && y0 < HIN) ? 1.f : 0.f;
        float vy1 = (y1 >= 0 && y1 < HIN) ? 1.f : 0.f;
        float vx0 = (x0 >= 0 && x0 < WIN) ? 1.f : 0.f;
        float vx1 = (x1 >= 0 && x1 < WIN) ? 1.f : 0.f;
        int y0c = min(max(y0, 0), HIN - 1);
        int y1c = min(max(y1, 0), HIN - 1);
        int x0c = min(max(x0, 0), WIN - 1);
        int x1c = min(max(x1, 0), WIN - 1);
        int o00 = y0c * WIN + x0c;
        int o01 = y0c * WIN + x1c;
        int o10 = y1c * WIN + x0c;
        int o11 = y1c * WIN + x1c;
        float w00 = (1.f - fy) * (1.f - fx) * vy0 * vx0;   // validity folded into weights
        float w01 = (1.f - fy) * fx         * vy0 * vx1;
        float w10 = fy * (1.f - fx)         * vy1 * vx0;
        float w11 = fy * fx                 * vy1 * vx1;

        const float* pc   = inp_n + cbase * (HIN * WIN);
        const float* wrow = wT + ((k * CIN + cbase) << 6);
#pragma unroll 4
        for (int c = 0; c < 16; ++c) {
            float v = w00 * pc[o00] + w01 * pc[o01] + w10 * pc[o10] + w11 * pc[o11];
#pragma unroll
            for (int co = 0; co < COUT; ++co)
                acc[co] = fmaf(v, wrow[co], acc[co]);
            pc   += HIN * WIN;
            wrow += COUT;
        }
    }

    // reduce the 4 cin-group partial sums: red[co][wo]
    __shared__ float red[COUT * WOUT];            // 16 KB
    for (int i = tid; i < COUT * WOUT; i += 256) red[i] = 0.f;
    __syncthreads();
#pragma unroll
    for (int co = 0; co < COUT; ++co)
        atomicAdd(&red[co * WOUT + wo], acc[co]); // native ds_add_f32, stride-1 across lanes
    __syncthreads();

    float* out_p = out + (n * COUT * HOUT + ho) * WOUT;
    for (int i = tid; i < COUT * WOUT; i += 256) {
        int co = i >> 6, w2 = i & 63;
        out_p[co * (HOUT * WOUT) + w2] = red[i];
    }
}

extern "C" void kernel_launch(void* const* d_in, const int* in_sizes, int n_in,
                              void* d_out, int out_size, void* d_ws, size_t ws_size,
                              hipStream_t stream) {
    const float* inp = (const float*)d_in[0];
    const float* off = (const float*)d_in[1];
    const float* w   = (const float*)d_in[2];
    float* wT  = (float*)d_ws;                    // 9*64*64*4 = 147456 B
    float* out = (float*)d_out;

    repack_w_kernel<<<(KK * CIN * COUT + 255) / 256, 256, 0, stream>>>(w, wT);
    dconv_kernel<<<NB * HOUT, 256, 0, stream>>>(inp, off, wT, out);
}

// Round 3
// 160.396 us; speedup vs baseline: 1.3439x; 1.0166x over previous
//
#include <hip/hip_runtime.h>

#define NB    16
#define CIN   64
#define COUT  64
#define HIN   66
#define WIN   66
#define HOUT  64
#define WOUT  64
#define KK    9
#define NXCD  8
#define KCH   3

// ---------------- new path: NHWC + LDS-staged sampling + scalar-W GEMM ----------------

// weight [cout][cin][k] -> wT2[g][k][c][j]  (g=cout>>4, j=cout&15; contiguous per wave)
__global__ __launch_bounds__(256) void repack_w2(const float* __restrict__ w,
                                                 float* __restrict__ wT2) {
    int i = blockIdx.x * 256 + threadIdx.x;
    if (i >= 4 * KK * CIN * 16) return;
    int j = i & 15; int t = i >> 4;
    int c = t & 63; t >>= 6;
    int k = t % KK; int g = t / KK;
    wT2[i] = w[((g * 16 + j) * CIN + c) * KK + k];
}

// input NCHW -> NHWC (channels contiguous). block = (n, y); LDS transpose.
__global__ __launch_bounds__(256) void repack_inp(const float* __restrict__ in,
                                                  float* __restrict__ nhwc) {
    int b = blockIdx.x;
    int n = b / HIN, y = b % HIN;
    __shared__ float buf[CIN * 67];              // pad 66->67: phase-2 read 2-way (free)
    const float* src = in + (size_t)(n * CIN) * HIN * WIN + y * WIN;
    for (int i = threadIdx.x; i < CIN * WIN; i += 256) {
        int c = i / WIN, x = i - c * WIN;        // consecutive i -> consecutive x: coalesced
        buf[c * 67 + x] = src[c * (HIN * WIN) + x];
    }
    __syncthreads();
    float* dst = nhwc + (size_t)((n * HIN + y) * WIN) * CIN;
    for (int i = threadIdx.x; i < CIN * WIN; i += 256) {
        int x = i >> 6, c = i & 63;              // consecutive i -> consecutive c: coalesced store
        dst[x * CIN + c] = buf[c * 67 + x];
    }
}

__global__ __launch_bounds__(256) void dconv2(const float* __restrict__ nhwc,
                                              const float* __restrict__ off,
                                              const float* __restrict__ wT2,
                                              float* __restrict__ out) {
    const int tid  = threadIdx.x;
    const int lane = tid & 63;
    const int wv   = tid >> 6;
    // XCD-aware chunked swizzle (grid 1024, bijective)
    const int p0 = blockIdx.x;
    const int logical = (p0 & (NXCD - 1)) * (NB * HOUT / NXCD) + (p0 >> 3);
    const int n  = logical >> 6;
    const int ho = logical & 63;
    const int g  = __builtin_amdgcn_readfirstlane(wv);   // cout group, wave-uniform

    __shared__ float vt[KCH * 64 * 65];          // [k3*64+c][wo], 49920 B

    float acc[16];
#pragma unroll
    for (int j = 0; j < 16; ++j) acc[j] = 0.f;

    const float* nh_n  = nhwc + (size_t)n * (HIN * WIN * CIN);
    const float* off_n = off + (size_t)n * (2 * KK * HOUT * WOUT) + ho * WOUT;
    const float* wgp0  = wT2 + (g * KK * 64) * 16;

#pragma unroll 1
    for (int kb = 0; kb < KK; kb += KCH) {
        // ---- sampling: 192 (k3,wo) pairs, 48 per wave, lanes = channels ----
#pragma unroll 2
        for (int pp = 0; pp < 48; ++pp) {
            int p  = wv * 48 + pp;
            int k3 = p >> 6, wo = p & 63;
            int k  = kb + k3;
            float dy = off_n[(2 * k) * (HOUT * WOUT) + wo];     // broadcast (uniform addr)
            float dx = off_n[(2 * k + 1) * (HOUT * WOUT) + wo];
            float py = (float)(ho + k / 3) + dy;
            float px = (float)(wo + k % 3) + dx;
            float y0f = floorf(py), x0f = floorf(px);
            float fy = py - y0f, fx = px - x0f;
            int y0 = (int)y0f, x0 = (int)x0f;
            int y1 = y0 + 1,   x1 = x0 + 1;
            float w00 = (1.f - fy) * (1.f - fx) * ((y0 >= 0 && y0 < HIN && x0 >= 0 && x0 < WIN) ? 1.f : 0.f);
            float w01 = (1.f - fy) * fx         * ((y0 >= 0 && y0 < HIN && x1 >= 0 && x1 < WIN) ? 1.f : 0.f);
            float w10 = fy * (1.f - fx)         * ((y1 >= 0 && y1 < HIN && x0 >= 0 && x0 < WIN) ? 1.f : 0.f);
            float w11 = fy * fx                 * ((y1 >= 0 && y1 < HIN && x1 >= 0 && x1 < WIN) ? 1.f : 0.f);
            int y0c = min(max(y0, 0), HIN - 1), y1c = min(max(y1, 0), HIN - 1);
            int x0c = min(max(x0, 0), WIN - 1), x1c = min(max(x1, 0), WIN - 1);
            const float* b00 = nh_n + (y0c * WIN + x0c) * CIN;  // 256 B coalesced each
            const float* b01 = nh_n + (y0c * WIN + x1c) * CIN;
            const float* b10 = nh_n + (y1c * WIN + x0c) * CIN;
            const float* b11 = nh_n + (y1c * WIN + x1c) * CIN;
            float v = w00 * b00[lane] + w01 * b01[lane] + w10 * b10[lane] + w11 * b11[lane];
            vt[(k3 * 64 + lane) * 65 + wo] = v;   // lanes=c, stride 65 -> bank (c+wo)%32: 2-way, free
        }
        __syncthreads();
        // ---- GEMM: thread (wo=lane, cout-group g): 192 kc x 16 couts ----
        const float* wgp = wgp0 + (kb * 64) * 16;
#pragma unroll 4
        for (int kc = 0; kc < KCH * 64; ++kc) {
            float vv = vt[kc * 65 + lane];        // lanes contiguous: conflict-free
            const float* wp = wgp + kc * 16;      // wave-uniform -> scalar loads
#pragma unroll
            for (int j = 0; j < 16; ++j) acc[j] = fmaf(vv, wp[j], acc[j]);
        }
        __syncthreads();
    }
    float* op = out + (size_t)((n * COUT + g * 16) * HOUT + ho) * WOUT + lane;
#pragma unroll
    for (int j = 0; j < 16; ++j) op[j * (HOUT * WOUT)] = acc[j];  // coalesced
}

// ---------------- fallback (R2 kernel) if ws too small for NHWC buffer ----------------

__global__ __launch_bounds__(256) void repack_w_kernel(const float* __restrict__ w,
                                                       float* __restrict__ wT) {
    int i = blockIdx.x * 256 + threadIdx.x;
    if (i >= KK * CIN * COUT) return;
    int co = i & 63; int t = i >> 6;
    int c = t & 63;  int k = t >> 6;
    wT[i] = w[(co * CIN + c) * KK + k];
}

__global__ __launch_bounds__(256) void dconv_kernel(const float* __restrict__ inp,
                                                    const float* __restrict__ off,
                                                    const float* __restrict__ wT,
                                                    float* __restrict__ out) {
    const int tid = threadIdx.x;
    const int wo  = tid & 63;
    const int g   = tid >> 6;
    const int p   = blockIdx.x;
    const int logical = (p & (NXCD - 1)) * (NB * HOUT / NXCD) + (p >> 3);
    const int n   = logical >> 6;
    const int ho  = logical & 63;
    const int cbase = __builtin_amdgcn_readfirstlane(g << 4);
    float acc[COUT];
#pragma unroll
    for (int i = 0; i < COUT; ++i) acc[i] = 0.f;
    const float* inp_n = inp + n * (CIN * HIN * WIN);
    const float* off_p = off + ((n * (2 * KK)) * HOUT + ho) * WOUT + wo;
#pragma unroll 1
    for (int k = 0; k < KK; ++k) {
        float dy = off_p[(2 * k) * (HOUT * WOUT)];
        float dx = off_p[(2 * k + 1) * (HOUT * WOUT)];
        float py = (float)(ho + k / 3) + dy;
        float px = (float)(wo + k % 3) + dx;
        float y0f = floorf(py), x0f = floorf(px);
        float fy = py - y0f, fx = px - x0f;
        int y0 = (int)y0f, x0 = (int)x0f;
        int y1 = y0 + 1,   x1 = x0 + 1;
        float vy0 = (y0 >= 0 && y0 < HIN) ? 1.f : 0.f;
        float vy1 = (y1 >= 0 && y1 < HIN) ? 1.f : 0.f;
        float vx0 = (x0 >= 0 && x0 < WIN) ? 1.f : 0.f;
        float vx1 = (x1 >= 0 && x1 < WIN) ? 1.f : 0.f;
        int y0c = min(max(y0, 0), HIN - 1), y1c = min(max(y1, 0), HIN - 1);
        int x0c = min(max(x0, 0), WIN - 1), x1c = min(max(x1, 0), WIN - 1);
        int o00 = y0c * WIN + x0c, o01 = y0c * WIN + x1c;
        int o10 = y1c * WIN + x0c, o11 = y1c * WIN + x1c;
        float w00 = (1.f - fy) * (1.f - fx) * vy0 * vx0;
        float w01 = (1.f - fy) * fx * vy0 * vx1;
        float w10 = fy * (1.f - fx) * vy1 * vx0;
        float w11 = fy * fx * vy1 * vx1;
        const float* pc   = inp_n + cbase * (HIN * WIN);
        const float* wrow = wT + ((k * CIN + cbase) << 6);
#pragma unroll 4
        for (int c = 0; c < 16; ++c) {
            float v = w00 * pc[o00] + w01 * pc[o01] + w10 * pc[o10] + w11 * pc[o11];
#pragma unroll
            for (int co = 0; co < COUT; ++co) acc[co] = fmaf(v, wrow[co], acc[co]);
            pc += HIN * WIN; wrow += COUT;
        }
    }
    __shared__ float red[COUT * WOUT];
    for (int i = tid; i < COUT * WOUT; i += 256) red[i] = 0.f;
    __syncthreads();
#pragma unroll
    for (int co = 0; co < COUT; ++co) atomicAdd(&red[co * WOUT + wo], acc[co]);
    __syncthreads();
    float* out_p = out + (n * COUT * HOUT + ho) * WOUT;
    for (int i = tid; i < COUT * WOUT; i += 256) {
        int co = i >> 6, w2 = i & 63;
        out_p[co * (HOUT * WOUT) + w2] = red[i];
    }
}

extern "C" void kernel_launch(void* const* d_in, const int* in_sizes, int n_in,
                              void* d_out, int out_size, void* d_ws, size_t ws_size,
                              hipStream_t stream) {
    const float* inp = (const float*)d_in[0];
    const float* off = (const float*)d_in[1];
    const float* w   = (const float*)d_in[2];
    float* out = (float*)d_out;

    const size_t nhwc_bytes = (size_t)NB * HIN * WIN * CIN * sizeof(float); // 17,842,176
    const size_t wT2_bytes  = (size_t)4 * KK * CIN * 16 * sizeof(float);    // 147,456

    if (ws_size >= nhwc_bytes + wT2_bytes) {
        float* nhwc = (float*)d_ws;
        float* wT2  = (float*)((char*)d_ws + nhwc_bytes);
        repack_w2<<<(4 * KK * CIN * 16 + 255) / 256, 256, 0, stream>>>(w, wT2);
        repack_inp<<<NB * HIN, 256, 0, stream>>>(inp, nhwc);
        dconv2<<<NB * HOUT, 256, 0, stream>>>(nhwc, off, wT2, out);
    } else {
        float* wT = (float*)d_ws;
        repack_w_kernel<<<(KK * CIN * COUT + 255) / 256, 256, 0, stream>>>(w, wT);
        dconv_kernel<<<NB * HOUT, 256, 0, stream>>>(inp, off, wT, out);
    }
}

// Round 4
// 71.702 us; speedup vs baseline: 3.0063x; 2.2370x over previous
//
#include <hip/hip_runtime.h>
#include <hip/hip_bf16.h>

#define NB    16
#define CIN   64
#define COUT  64
#define HIN   66
#define WIN   66
#define HOUT  64
#define WOUT  64
#define KK    9
#define NXCD  8

typedef __attribute__((ext_vector_type(8))) short bf16x8;
typedef __attribute__((ext_vector_type(4))) float f32x4;

static __device__ __forceinline__ unsigned short f2bf(float f) {
    union { float f; unsigned int u; } x; x.f = f;
    unsigned int r = x.u + 0x7fff + ((x.u >> 16) & 1);   // RNE
    return (unsigned short)(r >> 16);
}

// ---------------- repack: NCHW -> NHWC f32 ----------------
__global__ __launch_bounds__(256) void repack_inp(const float* __restrict__ in,
                                                  float* __restrict__ nhwc) {
    int b = blockIdx.x;
    int n = b / HIN, y = b % HIN;
    __shared__ float buf[CIN * 67];
    const float* src = in + (size_t)(n * CIN) * HIN * WIN + y * WIN;
    for (int i = threadIdx.x; i < CIN * WIN; i += 256) {
        int c = i / WIN, x = i - c * WIN;
        buf[c * 67 + x] = src[c * (HIN * WIN) + x];
    }
    __syncthreads();
    float* dst = nhwc + (size_t)((n * HIN + y) * WIN) * CIN;
    for (int i = threadIdx.x; i < CIN * WIN; i += 256) {
        int x = i >> 6, c = i & 63;
        dst[x * CIN + c] = buf[c * 67 + x];
    }
}

// ---------------- repack: weights -> pre-swizzled bf16 LDS image ----------------
// wS[kb][row=cout][k_local=0..191], k_local = (tap-3kb)*64 + cin,
// byte image per kb: row*384 + ((slot ^ (row&7))<<4) + (k&7)*2, slot=k>>3.
__global__ __launch_bounds__(256) void repack_wS(const float* __restrict__ w,
                                                 unsigned short* __restrict__ wS) {
    int i = blockIdx.x * 256 + threadIdx.x;
    if (i >= 3 * 64 * 192) return;
    int kb  = i / 12288;
    int rem = i - kb * 12288;
    int cout = rem / 192;
    int kl   = rem - cout * 192;
    int tap  = kb * 3 + (kl >> 6);
    int cin  = kl & 63;
    float v = w[(cout * CIN + cin) * KK + tap];
    int slot = (kl >> 3) ^ (cout & 7);
    int byte = kb * 24576 + cout * 384 + (slot << 4) + (kl & 7) * 2;
    wS[byte >> 1] = f2bf(v);
}

// ---------------- main: implicit-GEMM deformable conv via MFMA ----------------
__global__ __launch_bounds__(256) void dconv3(const float* __restrict__ nhwc,
                                              const float* __restrict__ off,
                                              const unsigned short* __restrict__ wS,
                                              float* __restrict__ out) {
    __shared__ __align__(16) char sm[60672];
    char* smS = sm;                                    // 24576: sampled tile image
    char* smW = sm + 24576;                            // 24576: weight tile image
    int*  sA  = (int*)(sm + 49152);                    // 576 packed addrs (2304 B)
    float* sWf = (float*)(sm + 51456);                 // 576*4 f32 bilinear wts (9216 B)

    const int tid  = threadIdx.x;
    const int lane = tid & 63;
    const int wv   = tid >> 6;
    const int p0 = blockIdx.x;
    const int logical = (p0 & (NXCD - 1)) * (NB * HOUT / NXCD) + (p0 >> 3);
    const int n  = logical >> 6;
    const int ho = logical & 63;

    const float* nh_n  = nhwc + (size_t)n * (HIN * WIN * CIN);
    const float* off_n = off + (size_t)n * (2 * KK * HOUT * WOUT) + ho * WOUT;

    // ---- S1: bilinear meta per (tap, wo): packed base addr + step flags + 4 wts ----
    for (int q = tid; q < KK * 64; q += 256) {
        int k  = q >> 6;
        int wo = q & 63;
        float dy = off_n[(2 * k) * (HOUT * WOUT) + wo];
        float dx = off_n[(2 * k + 1) * (HOUT * WOUT) + wo];
        int kh = (k * 171) >> 9;                       // k/3 for k<9
        int kw = k - 3 * kh;
        float py = (float)(ho + kh) + dy;
        float px = (float)(wo + kw) + dx;
        float y0f = floorf(py), x0f = floorf(px);
        float fy = py - y0f, fx = px - x0f;
        int y0 = (int)y0f, x0 = (int)x0f;
        int y1 = y0 + 1,   x1 = x0 + 1;
        float vy0 = (y0 >= 0 && y0 < HIN) ? 1.f : 0.f;
        float vy1 = (y1 >= 0 && y1 < HIN) ? 1.f : 0.f;
        float vx0 = (x0 >= 0 && x0 < WIN) ? 1.f : 0.f;
        float vx1 = (x1 >= 0 && x1 < WIN) ? 1.f : 0.f;
        int y0c = min(max(y0, 0), HIN - 1), y1c = min(max(y1, 0), HIN - 1);
        int x0c = min(max(x0, 0), WIN - 1), x1c = min(max(x1, 0), WIN - 1);
        int a00 = (y0c * WIN + x0c) * CIN;             // <2^19
        int sx  = x1c - x0c;                           // 0/1
        int sy  = y1c - y0c;                           // 0/1
        sA[q] = a00 | (sx << 20) | (sy << 21);
        sWf[q * 4 + 0] = (1.f - fy) * (1.f - fx) * vy0 * vx0;
        sWf[q * 4 + 1] = (1.f - fy) * fx         * vy0 * vx1;
        sWf[q * 4 + 2] = fy * (1.f - fx)         * vy1 * vx0;
        sWf[q * 4 + 3] = fy * fx                 * vy1 * vx1;
    }
    __syncthreads();

    f32x4 acc[4];
#pragma unroll
    for (int ct = 0; ct < 4; ++ct) acc[ct] = (f32x4){0.f, 0.f, 0.f, 0.f};

#pragma unroll 1
    for (int kb = 0; kb < 3; ++kb) {
        // stage W chunk (pre-swizzled image) into regs early — lands during gather
        int4 wreg[6];
        const int4* wsrc = (const int4*)wS + kb * 1536 + tid;
#pragma unroll
        for (int i = 0; i < 6; ++i) wreg[i] = wsrc[i * 256];

        // ---- S2: gather 192 (tap,wo) pairs, 48 per wave, lanes = channels ----
#pragma unroll 4
        for (int pp = 0; pp < 48; ++pp) {
            int p = wv * 48 + pp;
            int q = kb * 192 + p;
            int av = sA[q];                            // broadcast reads
            float4 wt = *(const float4*)&sWf[q * 4];
            int a00 = av & 0xFFFFF;
            int a01 = a00 + ((av >> 14) & 64);         // +CIN if x-step
            int a10 = a00 + ((av >> 21) & 1) * (WIN * CIN);
            int a11 = a10 + (a01 - a00);
            float g00 = nh_n[a00 + lane];
            float g01 = nh_n[a01 + lane];
            float g10 = nh_n[a10 + lane];
            float g11 = nh_n[a11 + lane];
            float v = wt.x * g00 + wt.y * g01 + wt.z * g10 + wt.w * g11;
            int k3 = p >> 6, wo = p & 63;
            int slot = (k3 * 8 + (lane >> 3)) ^ (wo & 7);
            *(unsigned short*)(smS + wo * 384 + (slot << 4) + (lane & 7) * 2) = f2bf(v);
        }
        // write W image to LDS (linear copy — source is pre-swizzled)
#pragma unroll
        for (int i = 0; i < 6; ++i) *((int4*)smW + i * 256 + tid) = wreg[i];
        __syncthreads();

        // ---- GEMM: wave wv owns pixel rows [16wv,16wv+16), 4 cout tiles ----
        const int row = 16 * wv + (lane & 15);
        const int h   = lane >> 4;
#pragma unroll
        for (int ks = 0; ks < 6; ++ks) {
            int aslot = (ks * 4 + h) ^ (row & 7);
            bf16x8 af = *(const bf16x8*)(smS + row * 384 + (aslot << 4));
#pragma unroll
            for (int ct = 0; ct < 4; ++ct) {
                int brow = 16 * ct + (lane & 15);
                int bslot = (ks * 4 + h) ^ (brow & 7);
                bf16x8 bf = *(const bf16x8*)(smW + brow * 384 + (bslot << 4));
                acc[ct] = __builtin_amdgcn_mfma_f32_16x16x32_bf16(af, bf, acc[ct], 0, 0, 0);
            }
        }
        __syncthreads();                               // S tile reused next kb
    }

    // ---- epilogue: transpose through LDS for coalesced stores ----
    float* red = (float*)sm;                           // [64 couts][65], overlays smS
#pragma unroll
    for (int ct = 0; ct < 4; ++ct)
#pragma unroll
        for (int r = 0; r < 4; ++r)
            red[(16 * ct + (lane & 15)) * 65 + (16 * wv + (lane >> 4) * 4 + r)] = acc[ct][r];
    __syncthreads();
    float* op = out + (size_t)(n * COUT) * (HOUT * WOUT) + ho * WOUT + lane;
#pragma unroll
    for (int j = 0; j < 16; ++j) {
        int co = wv * 16 + j;
        op[(size_t)co * (HOUT * WOUT)] = red[co * 65 + lane];
    }
}

// ---------------- fallback (R2 path) if ws too small ----------------
__global__ __launch_bounds__(256) void repack_w_kernel(const float* __restrict__ w,
                                                       float* __restrict__ wT) {
    int i = blockIdx.x * 256 + threadIdx.x;
    if (i >= KK * CIN * COUT) return;
    int co = i & 63; int t = i >> 6;
    int c = t & 63;  int k = t >> 6;
    wT[i] = w[(co * CIN + c) * KK + k];
}

__global__ __launch_bounds__(256) void dconv_kernel(const float* __restrict__ inp,
                                                    const float* __restrict__ off,
                                                    const float* __restrict__ wT,
                                                    float* __restrict__ out) {
    const int tid = threadIdx.x;
    const int wo  = tid & 63;
    const int g   = tid >> 6;
    const int p   = blockIdx.x;
    const int logical = (p & (NXCD - 1)) * (NB * HOUT / NXCD) + (p >> 3);
    const int n   = logical >> 6;
    const int ho  = logical & 63;
    const int cbase = __builtin_amdgcn_readfirstlane(g << 4);
    float acc[COUT];
#pragma unroll
    for (int i = 0; i < COUT; ++i) acc[i] = 0.f;
    const float* inp_n = inp + n * (CIN * HIN * WIN);
    const float* off_p = off + ((n * (2 * KK)) * HOUT + ho) * WOUT + wo;
#pragma unroll 1
    for (int k = 0; k < KK; ++k) {
        float dy = off_p[(2 * k) * (HOUT * WOUT)];
        float dx = off_p[(2 * k + 1) * (HOUT * WOUT)];
        float py = (float)(ho + k / 3) + dy;
        float px = (float)(wo + k % 3) + dx;
        float y0f = floorf(py), x0f = floorf(px);
        float fy = py - y0f, fx = px - x0f;
        int y0 = (int)y0f, x0 = (int)x0f;
        int y1 = y0 + 1,   x1 = x0 + 1;
        float vy0 = (y0 >= 0 && y0 < HIN) ? 1.f : 0.f;
        float vy1 = (y1 >= 0 && y1 < HIN) ? 1.f : 0.f;
        float vx0 = (x0 >= 0 && x0 < WIN) ? 1.f : 0.f;
        float vx1 = (x1 >= 0 && x1 < WIN) ? 1.f : 0.f;
        int y0c = min(max(y0, 0), HIN - 1), y1c = min(max(y1, 0), HIN - 1);
        int x0c = min(max(x0, 0), WIN - 1), x1c = min(max(x1, 0), WIN - 1);
        int o00 = y0c * WIN + x0c, o01 = y0c * WIN + x1c;
        int o10 = y1c * WIN + x0c, o11 = y1c * WIN + x1c;
        float w00 = (1.f - fy) * (1.f - fx) * vy0 * vx0;
        float w01 = (1.f - fy) * fx * vy0 * vx1;
        float w10 = fy * (1.f - fx) * vy1 * vx0;
        float w11 = fy * fx * vy1 * vx1;
        const float* pc   = inp_n + cbase * (HIN * WIN);
        const float* wrow = wT + ((k * CIN + cbase) << 6);
#pragma unroll 4
        for (int c = 0; c < 16; ++c) {
            float v = w00 * pc[o00] + w01 * pc[o01] + w10 * pc[o10] + w11 * pc[o11];
#pragma unroll
            for (int co = 0; co < COUT; ++co) acc[co] = fmaf(v, wrow[co], acc[co]);
            pc += HIN * WIN; wrow += COUT;
        }
    }
    __shared__ float redf[COUT * WOUT];
    for (int i = tid; i < COUT * WOUT; i += 256) redf[i] = 0.f;
    __syncthreads();
#pragma unroll
    for (int co = 0; co < COUT; ++co) atomicAdd(&redf[co * WOUT + wo], acc[co]);
    __syncthreads();
    float* out_p = out + (n * COUT * HOUT + ho) * WOUT;
    for (int i = tid; i < COUT * WOUT; i += 256) {
        int co = i >> 6, w2 = i & 63;
        out_p[co * (HOUT * WOUT) + w2] = redf[i];
    }
}

extern "C" void kernel_launch(void* const* d_in, const int* in_sizes, int n_in,
                              void* d_out, int out_size, void* d_ws, size_t ws_size,
                              hipStream_t stream) {
    const float* inp = (const float*)d_in[0];
    const float* off = (const float*)d_in[1];
    const float* w   = (const float*)d_in[2];
    float* out = (float*)d_out;

    const size_t nhwc_bytes = (size_t)NB * HIN * WIN * CIN * sizeof(float); // 17,842,176
    const size_t wS_bytes   = 3 * 24576;                                    // 73,728

    if (ws_size >= nhwc_bytes + wS_bytes) {
        float* nhwc = (float*)d_ws;
        unsigned short* wS = (unsigned short*)((char*)d_ws + nhwc_bytes);
        repack_wS<<<(3 * 64 * 192 + 255) / 256, 256, 0, stream>>>(w, wS);
        repack_inp<<<NB * HIN, 256, 0, stream>>>(inp, nhwc);
        dconv3<<<NB * HOUT, 256, 0, stream>>>(nhwc, off, wS, out);
    } else {
        float* wT = (float*)d_ws;
        repack_w_kernel<<<(KK * CIN * COUT + 255) / 256, 256, 0, stream>>>(w, wT);
        dconv_kernel<<<NB * HOUT, 256, 0, stream>>>(inp, off, wT, out);
    }
}